// Round 2
// baseline (5179.817 us; speedup 1.0000x reference)
//
#include <hip/hip_runtime.h>
#include <hip/hip_fp16.h>

#define R_ET 8
#define DH 128

// ---------------- degree count per (dst, etype) ----------------
__global__ void count_kernel(const int* __restrict__ ei, const int* __restrict__ et,
                             int* __restrict__ cnt, int E) {
  int e = blockIdx.x * blockDim.x + threadIdx.x;
  if (e < E) atomicAdd(&cnt[ei[E + e] * R_ET + et[e]], 1);
}

// XOR swizzle: break the 8-stride fragment pattern across 32 banks.
// 2-way bank aliasing after swizzle (free per m136); 4-way (1.58x) without.
__device__ __forceinline__ int swz(int c) { return c ^ ((c & 32) ? 4 : 0); }

// ---------------- fused GEMM: y = A@root + bias ; t[r] = A@W[r] ----------------
// blockIdx.y == 0 -> y ; 1..8 -> t slab (cb-1). Tile 128x128, K=128 in 4 chunks of 32.
template <typename TT>
__global__ __launch_bounds__(256) void gemm_kernel(
    const float* __restrict__ A, int relu_in,
    const float* __restrict__ root, const float* __restrict__ W,
    const float* __restrict__ bias,
    float* __restrict__ y, TT* __restrict__ t, int N) {
  __shared__ float As[32 * 132];  // transposed [k][row swizzled], pad 132
  __shared__ float Bs[32 * 132];  // [k][col swizzled]
  const int tid = threadIdx.x;
  const int cb = blockIdx.y;
  const int rbase = blockIdx.x * 128;
  const float* Bp = (cb == 0) ? root : (W + (size_t)(cb - 1) * DH * DH);

  const int r0 = (tid >> 4) * 8;
  const int c0 = (tid & 15) * 8;
  float acc[8][8];
#pragma unroll
  for (int a = 0; a < 8; a++)
#pragma unroll
    for (int b = 0; b < 8; b++) acc[a][b] = 0.f;

  for (int kc = 0; kc < 4; kc++) {
    if (kc) __syncthreads();
#pragma unroll
    for (int it = 0; it < 4; it++) {
      int idx = it * 256 + tid;
      // A: 128 rows x 32 k
      int r = idx >> 3, k4 = (idx & 7) * 4;
      int grow = rbase + r;
      float4 v = make_float4(0.f, 0.f, 0.f, 0.f);
      if (grow < N) v = *(const float4*)&A[(size_t)grow * DH + kc * 32 + k4];
      if (relu_in) {
        v.x = fmaxf(v.x, 0.f); v.y = fmaxf(v.y, 0.f);
        v.z = fmaxf(v.z, 0.f); v.w = fmaxf(v.w, 0.f);
      }
      int rs = swz(r);
      As[(k4 + 0) * 132 + rs] = v.x;
      As[(k4 + 1) * 132 + rs] = v.y;
      As[(k4 + 2) * 132 + rs] = v.z;
      As[(k4 + 3) * 132 + rs] = v.w;
      // B: 32 k x 128 c
      int kk = idx >> 5, c4 = (idx & 31) * 4;
      float4 w = *(const float4*)&Bp[(size_t)(kc * 32 + kk) * DH + c4];
      *(float4*)&Bs[kk * 132 + swz(c4)] = w;
    }
    __syncthreads();
#pragma unroll
    for (int k = 0; k < 32; k++) {
      float av[8], bv[8];
      // NOTE: fragment halves live at swz(base) and swz(base+4) — NOT swz(base)+4.
      *(float4*)&av[0] = *(const float4*)&As[k * 132 + swz(r0)];
      *(float4*)&av[4] = *(const float4*)&As[k * 132 + swz(r0 + 4)];
      *(float4*)&bv[0] = *(const float4*)&Bs[k * 132 + swz(c0)];
      *(float4*)&bv[4] = *(const float4*)&Bs[k * 132 + swz(c0 + 4)];
#pragma unroll
      for (int a = 0; a < 8; a++)
#pragma unroll
        for (int b = 0; b < 8; b++) acc[a][b] = fmaf(av[a], bv[b], acc[a][b]);
    }
  }

  if (cb == 0) {
#pragma unroll
    for (int a = 0; a < 8; a++) {
      int row = rbase + r0 + a;
      if (row < N) {
        float4 o0 = make_float4(acc[a][0] + bias[c0 + 0], acc[a][1] + bias[c0 + 1],
                                acc[a][2] + bias[c0 + 2], acc[a][3] + bias[c0 + 3]);
        float4 o1 = make_float4(acc[a][4] + bias[c0 + 4], acc[a][5] + bias[c0 + 5],
                                acc[a][6] + bias[c0 + 6], acc[a][7] + bias[c0 + 7]);
        *(float4*)&y[(size_t)row * DH + c0] = o0;
        *(float4*)&y[(size_t)row * DH + c0 + 4] = o1;
      }
    }
  } else {
    TT* tp = t + (size_t)(cb - 1) * N * DH;
#pragma unroll
    for (int a = 0; a < 8; a++) {
      int row = rbase + r0 + a;
      if (row < N) {
        if constexpr (sizeof(TT) == 4) {
          float* fp = (float*)tp;
          float4 o0 = make_float4(acc[a][0], acc[a][1], acc[a][2], acc[a][3]);
          float4 o1 = make_float4(acc[a][4], acc[a][5], acc[a][6], acc[a][7]);
          *(float4*)&fp[(size_t)row * DH + c0] = o0;
          *(float4*)&fp[(size_t)row * DH + c0 + 4] = o1;
        } else {
          __half* hp = (__half*)tp;
#pragma unroll
          for (int b = 0; b < 8; b++)
            hp[(size_t)row * DH + c0 + b] = __float2half(acc[a][b]);
        }
      }
    }
  }
}

// ---------------- edge scatter: y[dst] += t[et][src] / cnt ----------------
template <typename TT>
__global__ __launch_bounds__(256) void scatter_kernel(
    const int* __restrict__ ei, const int* __restrict__ et,
    const int* __restrict__ cnt, const TT* __restrict__ t,
    float* __restrict__ y, int N, int E) {
  int e = blockIdx.x * 4 + (threadIdx.x >> 6);
  if (e >= E) return;
  int lane = threadIdx.x & 63;
  int src = ei[e], dst = ei[E + e], r = et[e];
  float inv = 1.f / (float)cnt[dst * R_ET + r];  // edge exists -> cnt >= 1
  size_t toff = ((size_t)r * N + src) * DH + lane * 2;
  float vx, vy;
  if constexpr (sizeof(TT) == 4) {
    float2 v = *(const float2*)&t[toff];
    vx = v.x; vy = v.y;
  } else {
    __half2 v = *(const __half2*)&t[toff];
    vx = __half2float(v.x); vy = __half2float(v.y);
  }
  size_t yoff = (size_t)dst * DH + lane * 2;
  atomicAdd(&y[yoff], vx * inv);
  atomicAdd(&y[yoff + 1], vy * inv);
}

// ---------------- column sums for mean pool ----------------
__global__ __launch_bounds__(256) void pool_kernel(const float* __restrict__ y,
                                                   float* __restrict__ u, int N) {
  __shared__ float s[256];
  int tid = threadIdx.x;
  int c = tid & 127, rr = tid >> 7;
  int n0 = blockIdx.x * 100;
  int nend = min(n0 + 100, N);
  float sum = 0.f;
  for (int n = n0 + rr; n < nend; n += 2) sum += y[(size_t)n * DH + c];
  s[tid] = sum;
  __syncthreads();
  if (tid < 128) atomicAdd(&u[c], s[tid] + s[tid + 128]);
}

// ---------------- final MLP on concat(u1,u2)/N ----------------
__global__ __launch_bounds__(256) void mlp_kernel(
    const float* __restrict__ u, const float* __restrict__ fc1w,
    const float* __restrict__ fc1b, const float* __restrict__ fc2w,
    const float* __restrict__ fc2b, float* __restrict__ out, int N) {
  __shared__ float uin[256];
  __shared__ float hred[128];
  int tid = threadIdx.x;
  uin[tid] = u[tid] * (1.f / (float)N);
  __syncthreads();
  if (tid < 128) {
    float s = fc1b[tid];
    for (int i = 0; i < 256; i++) s = fmaf(uin[i], fc1w[i * 128 + tid], s);
    s = fmaxf(s, 0.f);
    hred[tid] = s * fc2w[tid];
  }
  __syncthreads();
  if (tid == 0) {
    float s = fc2b[0];
    for (int i = 0; i < 128; i++) s += hred[i];
    out[0] = s;
  }
}

extern "C" void kernel_launch(void* const* d_in, const int* in_sizes, int n_in,
                              void* d_out, int out_size, void* d_ws, size_t ws_size,
                              hipStream_t stream) {
  const float* x[2] = {(const float*)d_in[0], (const float*)d_in[3]};
  const int* ei[2] = {(const int*)d_in[1], (const int*)d_in[4]};
  const int* et[2] = {(const int*)d_in[2], (const int*)d_in[5]};
  const float* Wp[3] = {(const float*)d_in[6], (const float*)d_in[9], (const float*)d_in[12]};
  const float* rootp[3] = {(const float*)d_in[7], (const float*)d_in[10], (const float*)d_in[13]};
  const float* biasp[3] = {(const float*)d_in[8], (const float*)d_in[11], (const float*)d_in[14]};
  const float* fc1w = (const float*)d_in[15];
  const float* fc1b = (const float*)d_in[16];
  const float* fc2w = (const float*)d_in[17];
  const float* fc2b = (const float*)d_in[18];

  const int N = in_sizes[0] / DH;
  const int E = in_sizes[2];

  char* ws = (char*)d_ws;
  size_t off = 0;
  float* ya = (float*)(ws + off); off += (size_t)N * DH * 4;
  float* yb = (float*)(ws + off); off += (size_t)N * DH * 4;
  int* cnt  = (int*)(ws + off);   off += (size_t)N * R_ET * 4;
  float* u  = (float*)(ws + off); off += 1024;
  void* tbuf = (void*)(ws + off);
  const bool use_f32 = ws_size >= off + (size_t)R_ET * N * DH * sizeof(float);

  hipMemsetAsync(u, 0, 2 * DH * sizeof(float), stream);
  dim3 ggrid((N + 127) / 128, R_ET + 1);
  dim3 sgrid((E + 3) / 4);

  for (int g = 0; g < 2; g++) {
    hipMemsetAsync(cnt, 0, (size_t)N * R_ET * sizeof(int), stream);
    count_kernel<<<(E + 255) / 256, 256, 0, stream>>>(ei[g], et[g], cnt, E);
    for (int l = 0; l < 3; l++) {
      const float* Ai = (l == 0) ? x[g] : ((l == 1) ? ya : yb);
      float* yo = (l == 1) ? yb : ya;
      if (use_f32) {
        gemm_kernel<float><<<ggrid, 256, 0, stream>>>(Ai, l > 0, rootp[l], Wp[l],
                                                      biasp[l], yo, (float*)tbuf, N);
        scatter_kernel<float><<<sgrid, 256, 0, stream>>>(ei[g], et[g], cnt,
                                                         (const float*)tbuf, yo, N, E);
      } else {
        gemm_kernel<__half><<<ggrid, 256, 0, stream>>>(Ai, l > 0, rootp[l], Wp[l],
                                                       biasp[l], yo, (__half*)tbuf, N);
        scatter_kernel<__half><<<sgrid, 256, 0, stream>>>(ei[g], et[g], cnt,
                                                          (const __half*)tbuf, yo, N, E);
      }
    }
    pool_kernel<<<(N + 99) / 100, 256, 0, stream>>>(ya, u + g * DH, N);
  }
  mlp_kernel<<<1, 256, 0, stream>>>(u, fc1w, fc1b, fc2w, fc2b, (float*)d_out, N);
}

// Round 3
// 2209.313 us; speedup vs baseline: 2.3445x; 2.3445x over previous
//
#include <hip/hip_runtime.h>
#include <hip/hip_fp16.h>

#define R_ET 8
#define DH 128

// ---------------- degree count per (dst, etype) ----------------
__global__ void count_kernel(const int* __restrict__ ei, const int* __restrict__ et,
                             int* __restrict__ cnt, int E) {
  int e = blockIdx.x * blockDim.x + threadIdx.x;
  if (e < E) atomicAdd(&cnt[ei[E + e] * R_ET + et[e]], 1);
}

// ---------------- exclusive scan of per-dst degree -> CSR offsets ----------------
// Single 1024-thread block; N=50k -> 49 elems/thread sequential + block scan.
__global__ __launch_bounds__(1024) void scan_kernel(const int* __restrict__ cnt,
                                                    int* __restrict__ off,
                                                    int* __restrict__ cursor, int N) {
  __shared__ int s[1024];
  int tid = threadIdx.x;
  int chunk = (N + 1023) >> 10;
  int lo = tid * chunk, hi = min(lo + chunk, N);
  int sum = 0;
  for (int i = lo; i < hi; i++) {
    int d = 0;
#pragma unroll
    for (int r = 0; r < R_ET; r++) d += cnt[i * R_ET + r];
    sum += d;
  }
  s[tid] = sum;
  __syncthreads();
  for (int step = 1; step < 1024; step <<= 1) {
    int v = (tid >= step) ? s[tid - step] : 0;
    __syncthreads();
    s[tid] += v;
    __syncthreads();
  }
  int base = (tid == 0) ? 0 : s[tid - 1];
  for (int i = lo; i < hi; i++) {
    off[i] = base;
    cursor[i] = base;
    int d = 0;
#pragma unroll
    for (int r = 0; r < R_ET; r++) d += cnt[i * R_ET + r];
    base += d;
  }
  if (tid == 1023) off[N] = base;  // empty tail chunks keep base == E
}

// ---------------- place edges into dst-sorted slots ----------------
__global__ void place_kernel(const int* __restrict__ ei, const int* __restrict__ et,
                             const int* __restrict__ cnt, int* __restrict__ cursor,
                             int* __restrict__ sorted, float* __restrict__ scale, int E) {
  int e = blockIdx.x * blockDim.x + threadIdx.x;
  if (e >= E) return;
  int src = ei[e], dst = ei[E + e], r = et[e];
  int slot = atomicAdd(&cursor[dst], 1);
  sorted[slot] = src | (r << 28);  // src < 2^28, r < 8
  scale[slot] = 1.f / (float)cnt[dst * R_ET + r];  // edge exists -> cnt >= 1
}

// XOR swizzle: break the 8-stride fragment pattern across 32 banks (2-way = free).
__device__ __forceinline__ int swz(int c) { return c ^ ((c & 32) ? 4 : 0); }

// ---------------- fused GEMM: y = A@root + bias ; t[r] = A@W[r] ----------------
// blockIdx.y == 0 -> y ; 1..8 -> t slab (cb-1). Tile 128x128, K=128 in 4 chunks of 32.
template <typename TT>
__global__ __launch_bounds__(256) void gemm_kernel(
    const float* __restrict__ A, int relu_in,
    const float* __restrict__ root, const float* __restrict__ W,
    const float* __restrict__ bias,
    float* __restrict__ y, TT* __restrict__ t, int N) {
  __shared__ float As[32 * 132];  // transposed [k][row swizzled], pad 132
  __shared__ float Bs[32 * 132];  // [k][col swizzled]
  const int tid = threadIdx.x;
  const int cb = blockIdx.y;
  const int rbase = blockIdx.x * 128;
  const float* Bp = (cb == 0) ? root : (W + (size_t)(cb - 1) * DH * DH);

  const int r0 = (tid >> 4) * 8;
  const int c0 = (tid & 15) * 8;
  float acc[8][8];
#pragma unroll
  for (int a = 0; a < 8; a++)
#pragma unroll
    for (int b = 0; b < 8; b++) acc[a][b] = 0.f;

  for (int kc = 0; kc < 4; kc++) {
    if (kc) __syncthreads();
#pragma unroll
    for (int it = 0; it < 4; it++) {
      int idx = it * 256 + tid;
      int r = idx >> 3, k4 = (idx & 7) * 4;
      int grow = rbase + r;
      float4 v = make_float4(0.f, 0.f, 0.f, 0.f);
      if (grow < N) v = *(const float4*)&A[(size_t)grow * DH + kc * 32 + k4];
      if (relu_in) {
        v.x = fmaxf(v.x, 0.f); v.y = fmaxf(v.y, 0.f);
        v.z = fmaxf(v.z, 0.f); v.w = fmaxf(v.w, 0.f);
      }
      int rs = swz(r);
      As[(k4 + 0) * 132 + rs] = v.x;
      As[(k4 + 1) * 132 + rs] = v.y;
      As[(k4 + 2) * 132 + rs] = v.z;
      As[(k4 + 3) * 132 + rs] = v.w;
      int kk = idx >> 5, c4 = (idx & 31) * 4;
      float4 w = *(const float4*)&Bp[(size_t)(kc * 32 + kk) * DH + c4];
      *(float4*)&Bs[kk * 132 + swz(c4)] = w;
    }
    __syncthreads();
#pragma unroll
    for (int k = 0; k < 32; k++) {
      float av[8], bv[8];
      // fragment halves live at swz(base) and swz(base+4) — NOT swz(base)+4.
      *(float4*)&av[0] = *(const float4*)&As[k * 132 + swz(r0)];
      *(float4*)&av[4] = *(const float4*)&As[k * 132 + swz(r0 + 4)];
      *(float4*)&bv[0] = *(const float4*)&Bs[k * 132 + swz(c0)];
      *(float4*)&bv[4] = *(const float4*)&Bs[k * 132 + swz(c0 + 4)];
#pragma unroll
      for (int a = 0; a < 8; a++)
#pragma unroll
        for (int b = 0; b < 8; b++) acc[a][b] = fmaf(av[a], bv[b], acc[a][b]);
    }
  }

  if (cb == 0) {
#pragma unroll
    for (int a = 0; a < 8; a++) {
      int row = rbase + r0 + a;
      if (row < N) {
        float4 o0 = make_float4(acc[a][0] + bias[c0 + 0], acc[a][1] + bias[c0 + 1],
                                acc[a][2] + bias[c0 + 2], acc[a][3] + bias[c0 + 3]);
        float4 o1 = make_float4(acc[a][4] + bias[c0 + 4], acc[a][5] + bias[c0 + 5],
                                acc[a][6] + bias[c0 + 6], acc[a][7] + bias[c0 + 7]);
        *(float4*)&y[(size_t)row * DH + c0] = o0;
        *(float4*)&y[(size_t)row * DH + c0 + 4] = o1;
      }
    }
  } else {
    TT* tp = t + (size_t)(cb - 1) * N * DH;
#pragma unroll
    for (int a = 0; a < 8; a++) {
      int row = rbase + r0 + a;
      if (row < N) {
        if constexpr (sizeof(TT) == 4) {
          float* fp = (float*)tp;
          *(float4*)&fp[(size_t)row * DH + c0] =
              make_float4(acc[a][0], acc[a][1], acc[a][2], acc[a][3]);
          *(float4*)&fp[(size_t)row * DH + c0 + 4] =
              make_float4(acc[a][4], acc[a][5], acc[a][6], acc[a][7]);
        } else {
          __half* hp = (__half*)tp;
#pragma unroll
          for (int b = 0; b < 8; b++)
            hp[(size_t)row * DH + c0 + b] = __float2half(acc[a][b]);
        }
      }
    }
  }
}

// ---------------- CSR gather: y[dst] += sum_e scale_e * t[et_e][src_e] ----------------
// One wave per dst node; lane holds 2 columns; edge metadata batch-loaded + shfl-broadcast.
template <typename TT>
__global__ __launch_bounds__(256) void gather_kernel(
    const int* __restrict__ off, const int* __restrict__ sorted,
    const float* __restrict__ scale, const TT* __restrict__ t,
    float* __restrict__ y, int N) {
  int dst = blockIdx.x * 4 + (threadIdx.x >> 6);
  if (dst >= N) return;
  int lane = threadIdx.x & 63;
  int start = off[dst], end = off[dst + 1];
  float ax = 0.f, ay = 0.f;
  for (int base = start; base < end; base += 64) {
    int m = min(64, end - base);
    int p = 0;
    float s = 0.f;
    if (lane < m) { p = sorted[base + lane]; s = scale[base + lane]; }
    for (int j = 0; j < m; j++) {
      int pj = __shfl(p, j);
      float sj = __shfl(s, j);
      int src = pj & 0x0fffffff, r = pj >> 28;
      size_t toff = ((size_t)r * N + src) * DH + lane * 2;
      float vx, vy;
      if constexpr (sizeof(TT) == 4) {
        float2 v = *(const float2*)((const float*)t + toff);
        vx = v.x; vy = v.y;
      } else {
        __half2 v = *(const __half2*)((const __half*)t + toff);
        vx = __half2float(v.x); vy = __half2float(v.y);
      }
      ax = fmaf(vx, sj, ax);
      ay = fmaf(vy, sj, ay);
    }
  }
  float2* yp = (float2*)&y[(size_t)dst * DH + lane * 2];
  float2 yv = *yp;
  yv.x += ax; yv.y += ay;
  *yp = yv;
}

// ---------------- column sums for mean pool ----------------
__global__ __launch_bounds__(256) void pool_kernel(const float* __restrict__ y,
                                                   float* __restrict__ u, int N) {
  __shared__ float s[256];
  int tid = threadIdx.x;
  int c = tid & 127, rr = tid >> 7;
  int n0 = blockIdx.x * 100;
  int nend = min(n0 + 100, N);
  float sum = 0.f;
  for (int n = n0 + rr; n < nend; n += 2) sum += y[(size_t)n * DH + c];
  s[tid] = sum;
  __syncthreads();
  if (tid < 128) atomicAdd(&u[c], s[tid] + s[tid + 128]);
}

// ---------------- final MLP on concat(u1,u2)/N ----------------
__global__ __launch_bounds__(256) void mlp_kernel(
    const float* __restrict__ u, const float* __restrict__ fc1w,
    const float* __restrict__ fc1b, const float* __restrict__ fc2w,
    const float* __restrict__ fc2b, float* __restrict__ out, int N) {
  __shared__ float uin[256];
  __shared__ float hred[128];
  int tid = threadIdx.x;
  uin[tid] = u[tid] * (1.f / (float)N);
  __syncthreads();
  if (tid < 128) {
    float s = fc1b[tid];
    for (int i = 0; i < 256; i++) s = fmaf(uin[i], fc1w[i * 128 + tid], s);
    s = fmaxf(s, 0.f);
    hred[tid] = s * fc2w[tid];
  }
  __syncthreads();
  if (tid == 0) {
    float s = fc2b[0];
    for (int i = 0; i < 128; i++) s += hred[i];
    out[0] = s;
  }
}

extern "C" void kernel_launch(void* const* d_in, const int* in_sizes, int n_in,
                              void* d_out, int out_size, void* d_ws, size_t ws_size,
                              hipStream_t stream) {
  const float* x[2] = {(const float*)d_in[0], (const float*)d_in[3]};
  const int* ei[2] = {(const int*)d_in[1], (const int*)d_in[4]};
  const int* et[2] = {(const int*)d_in[2], (const int*)d_in[5]};
  const float* Wp[3] = {(const float*)d_in[6], (const float*)d_in[9], (const float*)d_in[12]};
  const float* rootp[3] = {(const float*)d_in[7], (const float*)d_in[10], (const float*)d_in[13]};
  const float* biasp[3] = {(const float*)d_in[8], (const float*)d_in[11], (const float*)d_in[14]};
  const float* fc1w = (const float*)d_in[15];
  const float* fc1b = (const float*)d_in[16];
  const float* fc2w = (const float*)d_in[17];
  const float* fc2b = (const float*)d_in[18];

  const int N = in_sizes[0] / DH;
  const int E = in_sizes[2];

  char* ws = (char*)d_ws;
  size_t off_b = 0;
  float* ya = (float*)(ws + off_b); off_b += (size_t)N * DH * 4;
  float* yb = (float*)(ws + off_b); off_b += (size_t)N * DH * 4;
  int* cnt = (int*)(ws + off_b); off_b += (size_t)N * R_ET * 4;
  int* offs = (int*)(ws + off_b); off_b += (size_t)(N + 1) * 4;
  int* cursor = (int*)(ws + off_b); off_b += (size_t)N * 4;
  int* sorted = (int*)(ws + off_b); off_b += (size_t)E * 4;
  float* scale = (float*)(ws + off_b); off_b += (size_t)E * 4;
  float* u = (float*)(ws + off_b); off_b += 1024;
  void* tbuf = (void*)(ws + off_b);
  const bool use_f32 = ws_size >= off_b + (size_t)R_ET * N * DH * sizeof(float);

  hipMemsetAsync(u, 0, 2 * DH * sizeof(float), stream);
  dim3 ggrid((N + 127) / 128, R_ET + 1);
  dim3 egrid((E + 255) / 256);
  dim3 ngrid((N + 3) / 4);

  for (int g = 0; g < 2; g++) {
    hipMemsetAsync(cnt, 0, (size_t)N * R_ET * sizeof(int), stream);
    count_kernel<<<egrid, 256, 0, stream>>>(ei[g], et[g], cnt, E);
    scan_kernel<<<1, 1024, 0, stream>>>(cnt, offs, cursor, N);
    place_kernel<<<egrid, 256, 0, stream>>>(ei[g], et[g], cnt, cursor, sorted, scale, E);
    for (int l = 0; l < 3; l++) {
      const float* Ai = (l == 0) ? x[g] : ((l == 1) ? ya : yb);
      float* yo = (l == 1) ? yb : ya;
      if (use_f32) {
        gemm_kernel<float><<<ggrid, 256, 0, stream>>>(Ai, l > 0, rootp[l], Wp[l],
                                                      biasp[l], yo, (float*)tbuf, N);
        gather_kernel<float><<<ngrid, 256, 0, stream>>>(offs, sorted, scale,
                                                        (const float*)tbuf, yo, N);
      } else {
        gemm_kernel<__half><<<ggrid, 256, 0, stream>>>(Ai, l > 0, rootp[l], Wp[l],
                                                       biasp[l], yo, (__half*)tbuf, N);
        gather_kernel<__half><<<ngrid, 256, 0, stream>>>(offs, sorted, scale,
                                                         (const __half*)tbuf, yo, N);
      }
    }
    pool_kernel<<<(N + 99) / 100, 256, 0, stream>>>(ya, u + g * DH, N);
  }
  mlp_kernel<<<1, 256, 0, stream>>>(u, fc1w, fc1b, fc2w, fc2b, (float*)d_out, N);
}

// Round 4
// 1341.912 us; speedup vs baseline: 3.8600x; 1.6464x over previous
//
#include <hip/hip_runtime.h>

#define R_ET 8
#define DH 128

typedef __bf16 bf16x8 __attribute__((ext_vector_type(8)));
typedef float f32x4 __attribute__((ext_vector_type(4)));

__device__ __forceinline__ ushort f2bf(float f) {
  unsigned u = __float_as_uint(f);
  u += 0x7fff + ((u >> 16) & 1);  // round-to-nearest-even
  return (ushort)(u >> 16);
}

// ---------------- degree count per (dst, etype) ----------------
__global__ void count_kernel(const int* __restrict__ ei, const int* __restrict__ et,
                             int* __restrict__ cnt, int E) {
  int e = blockIdx.x * blockDim.x + threadIdx.x;
  if (e < E) atomicAdd(&cnt[ei[E + e] * R_ET + et[e]], 1);
}

// ---------------- exclusive scan of per-dst degree -> CSR offsets ----------------
__global__ __launch_bounds__(1024) void scan_kernel(const int* __restrict__ cnt,
                                                    int* __restrict__ off,
                                                    int* __restrict__ cursor, int N) {
  __shared__ int s[1024];
  int tid = threadIdx.x;
  int chunk = (N + 1023) >> 10;
  int lo = tid * chunk, hi = min(lo + chunk, N);
  int sum = 0;
  for (int i = lo; i < hi; i++) {
    int d = 0;
#pragma unroll
    for (int r = 0; r < R_ET; r++) d += cnt[i * R_ET + r];
    sum += d;
  }
  s[tid] = sum;
  __syncthreads();
  for (int step = 1; step < 1024; step <<= 1) {
    int v = (tid >= step) ? s[tid - step] : 0;
    __syncthreads();
    s[tid] += v;
    __syncthreads();
  }
  int base = (tid == 0) ? 0 : s[tid - 1];
  for (int i = lo; i < hi; i++) {
    off[i] = base;
    cursor[i] = base;
    int d = 0;
#pragma unroll
    for (int r = 0; r < R_ET; r++) d += cnt[i * R_ET + r];
    base += d;
  }
  if (tid == 1023) off[N] = base;
}

// ---------------- place edges into dst-sorted slots ----------------
__global__ void place_kernel(const int* __restrict__ ei, const int* __restrict__ et,
                             const int* __restrict__ cnt, int* __restrict__ cursor,
                             int* __restrict__ sorted, float* __restrict__ scale, int E) {
  int e = blockIdx.x * blockDim.x + threadIdx.x;
  if (e >= E) return;
  int src = ei[e], dst = ei[E + e], r = et[e];
  int slot = atomicAdd(&cursor[dst], 1);
  sorted[slot] = src | (r << 28);  // src < 2^28, r < 8
  scale[slot] = 1.f / (float)cnt[dst * R_ET + r];
}

// ---------------- weight convert+transpose: Wt[mat][n][k] bf16 ----------------
__global__ __launch_bounds__(256) void wconv_kernel(const float* __restrict__ root,
                                                    const float* __restrict__ W,
                                                    ushort* __restrict__ Wt) {
  int mat = blockIdx.x;  // 0 = root, 1..8 = W[r]
  const float* src = (mat == 0) ? root : (W + (size_t)(mat - 1) * DH * DH);
  ushort* dst = Wt + (size_t)mat * DH * DH;
  for (int idx = threadIdx.x; idx < DH * DH; idx += 256) {
    int n = idx >> 7, k = idx & 127;
    dst[idx] = f2bf(src[k * DH + n]);
  }
}

// ---------------- activation convert (+optional ReLU), zero-pad rows ----------------
__global__ __launch_bounds__(256) void aconv_kernel(const float* __restrict__ src,
                                                    ushort* __restrict__ dst, int relu,
                                                    int total, int padtotal) {
  int i4 = (blockIdx.x * 256 + threadIdx.x) * 4;
  if (i4 >= padtotal) return;
  ushort4 o;
  if (i4 < total) {
    float4 v = *(const float4*)&src[i4];
    if (relu) {
      v.x = fmaxf(v.x, 0.f); v.y = fmaxf(v.y, 0.f);
      v.z = fmaxf(v.z, 0.f); v.w = fmaxf(v.w, 0.f);
    }
    o = make_ushort4(f2bf(v.x), f2bf(v.y), f2bf(v.z), f2bf(v.w));
  } else {
    o = make_ushort4(0, 0, 0, 0);
  }
  *(ushort4*)&dst[i4] = o;
}

// ---------------- bf16 MFMA GEMM: y = A@root + bias ; t[r] = A@W[r] (bf16 out) ----------
// blockIdx.y = cb: 0 -> y (fp32), 1..8 -> t slab cb-1 (bf16). 128x128 tile, BK=32.
// A: [Npad][128] bf16 row-major. Wt: [9][n][k] bf16 (B transposed). MFMA 16x16x32.
// Frag layouts (m89/m91-verified): A[m=lane&15][k=quad*8+j]; B[k=quad*8+j][n=lane&15];
// D[m=quad*4+reg][n=lane&15].
__global__ __launch_bounds__(256) void gemm_mfma(
    const ushort* __restrict__ Abf, const ushort* __restrict__ Wt,
    const float* __restrict__ bias, float* __restrict__ y,
    ushort* __restrict__ t, int N) {
  __shared__ ushort As[128 * 32];  // [row][kk] per K-chunk, contiguous (global_load_lds order)
  __shared__ ushort Bs[128 * 32];  // [n][kk]
  const int tid = threadIdx.x;
  const int wave = tid >> 6, lane = tid & 63;
  const int quad = lane >> 4, l15 = lane & 15;
  const int cb = blockIdx.y;
  const int rbase = blockIdx.x * 128;
  const ushort* gB = Wt + (size_t)cb * (DH * DH);
  const int wr = (wave >> 1) * 64, wc = (wave & 1) * 64;

  f32x4 acc[4][4];
#pragma unroll
  for (int i = 0; i < 4; i++)
#pragma unroll
    for (int j = 0; j < 4; j++) acc[i][j] = (f32x4){0.f, 0.f, 0.f, 0.f};

  for (int kc = 0; kc < 4; kc++) {
    if (kc) __syncthreads();
#pragma unroll
    for (int it = 0; it < 2; it++) {
      int piece = it * 256 + tid;              // 512 x 16B pieces = 8 KB tile
      int row = piece >> 2, sub = piece & 3;   // row-major [row][64B], 16B sub-pieces
      const ushort* ga = Abf + ((size_t)(rbase + row) * DH + kc * 32 + sub * 8);
      const ushort* gb = gB + ((size_t)row * DH + kc * 32 + sub * 8);
      // LDS dest: wave-uniform base + lane*16 (piece index of wave's lane 0)
      ushort* la = As + (size_t)(it * 256 + wave * 64) * 8;
      ushort* lb = Bs + (size_t)(it * 256 + wave * 64) * 8;
      __builtin_amdgcn_global_load_lds((const __attribute__((address_space(1))) void*)ga,
                                       (__attribute__((address_space(3))) void*)la, 16, 0, 0);
      __builtin_amdgcn_global_load_lds((const __attribute__((address_space(1))) void*)gb,
                                       (__attribute__((address_space(3))) void*)lb, 16, 0, 0);
    }
    __syncthreads();
    bf16x8 af[4], bfr[4];
#pragma unroll
    for (int i = 0; i < 4; i++) {
      af[i] = *(const bf16x8*)&As[(wr + i * 16 + l15) * 32 + quad * 8];
      bfr[i] = *(const bf16x8*)&Bs[(wc + i * 16 + l15) * 32 + quad * 8];
    }
#pragma unroll
    for (int i = 0; i < 4; i++)
#pragma unroll
      for (int j = 0; j < 4; j++)
        acc[i][j] = __builtin_amdgcn_mfma_f32_16x16x32_bf16(af[i], bfr[j], acc[i][j], 0, 0, 0);
  }

  if (cb == 0) {
#pragma unroll
    for (int j = 0; j < 4; j++) {
      int col = wc + j * 16 + l15;
      float bv = bias[col];
#pragma unroll
      for (int i = 0; i < 4; i++)
#pragma unroll
        for (int r = 0; r < 4; r++) {
          int row = rbase + wr + i * 16 + quad * 4 + r;
          if (row < N) y[(size_t)row * DH + col] = acc[i][j][r] + bv;
        }
    }
  } else {
    ushort* tp = t + (size_t)(cb - 1) * N * DH;
#pragma unroll
    for (int j = 0; j < 4; j++) {
      int col = wc + j * 16 + l15;
#pragma unroll
      for (int i = 0; i < 4; i++)
#pragma unroll
        for (int r = 0; r < 4; r++) {
          int row = rbase + wr + i * 16 + quad * 4 + r;
          if (row < N) tp[(size_t)row * DH + col] = f2bf(acc[i][j][r]);
        }
    }
  }
}

// ---------------- CSR gather: y[dst] += sum_e scale_e * t[et_e][src_e] ----------------
__global__ __launch_bounds__(256) void gather_kernel(
    const int* __restrict__ off, const int* __restrict__ sorted,
    const float* __restrict__ scale, const ushort* __restrict__ t,
    float* __restrict__ y, int N) {
  int dst = blockIdx.x * 4 + (threadIdx.x >> 6);
  if (dst >= N) return;
  int lane = threadIdx.x & 63;
  int start = off[dst], end = off[dst + 1];
  float ax = 0.f, ay = 0.f;
  for (int base = start; base < end; base += 64) {
    int m = min(64, end - base);
    int p = 0;
    float s = 0.f;
    if (lane < m) { p = sorted[base + lane]; s = scale[base + lane]; }
    for (int j = 0; j < m; j++) {
      int pj = __shfl(p, j);
      float sj = __shfl(s, j);
      int src = pj & 0x0fffffff, r = pj >> 28;
      unsigned u = *(const unsigned*)&t[((size_t)r * N + src) * DH + lane * 2];
      float vx = __uint_as_float(u << 16);
      float vy = __uint_as_float(u & 0xffff0000u);
      ax = fmaf(vx, sj, ax);
      ay = fmaf(vy, sj, ay);
    }
  }
  float2* yp = (float2*)&y[(size_t)dst * DH + lane * 2];
  float2 yv = *yp;
  yv.x += ax;
  yv.y += ay;
  *yp = yv;
}

// ---------------- column sums for mean pool ----------------
__global__ __launch_bounds__(256) void pool_kernel(const float* __restrict__ y,
                                                   float* __restrict__ u, int N) {
  __shared__ float s[256];
  int tid = threadIdx.x;
  int c = tid & 127, rr = tid >> 7;
  int n0 = blockIdx.x * 100;
  int nend = min(n0 + 100, N);
  float sum = 0.f;
  for (int n = n0 + rr; n < nend; n += 2) sum += y[(size_t)n * DH + c];
  s[tid] = sum;
  __syncthreads();
  if (tid < 128) atomicAdd(&u[c], s[tid] + s[tid + 128]);
}

// ---------------- final MLP on concat(u1,u2)/N ----------------
__global__ __launch_bounds__(256) void mlp_kernel(
    const float* __restrict__ u, const float* __restrict__ fc1w,
    const float* __restrict__ fc1b, const float* __restrict__ fc2w,
    const float* __restrict__ fc2b, float* __restrict__ out, int N) {
  __shared__ float uin[256];
  __shared__ float hred[128];
  int tid = threadIdx.x;
  uin[tid] = u[tid] * (1.f / (float)N);
  __syncthreads();
  if (tid < 128) {
    float s = fc1b[tid];
    for (int i = 0; i < 256; i++) s = fmaf(uin[i], fc1w[i * 128 + tid], s);
    s = fmaxf(s, 0.f);
    hred[tid] = s * fc2w[tid];
  }
  __syncthreads();
  if (tid == 0) {
    float s = fc2b[0];
    for (int i = 0; i < 128; i++) s += hred[i];
    out[0] = s;
  }
}

extern "C" void kernel_launch(void* const* d_in, const int* in_sizes, int n_in,
                              void* d_out, int out_size, void* d_ws, size_t ws_size,
                              hipStream_t stream) {
  const float* x[2] = {(const float*)d_in[0], (const float*)d_in[3]};
  const int* ei[2] = {(const int*)d_in[1], (const int*)d_in[4]};
  const int* et[2] = {(const int*)d_in[2], (const int*)d_in[5]};
  const float* Wp[3] = {(const float*)d_in[6], (const float*)d_in[9], (const float*)d_in[12]};
  const float* rootp[3] = {(const float*)d_in[7], (const float*)d_in[10], (const float*)d_in[13]};
  const float* biasp[3] = {(const float*)d_in[8], (const float*)d_in[11], (const float*)d_in[14]};
  const float* fc1w = (const float*)d_in[15];
  const float* fc1b = (const float*)d_in[16];
  const float* fc2w = (const float*)d_in[17];
  const float* fc2b = (const float*)d_in[18];

  const int N = in_sizes[0] / DH;
  const int E = in_sizes[2];
  const int Npad = (N + 127) & ~127;

  char* ws = (char*)d_ws;
  size_t ob = 0;
  auto alloc = [&](size_t bytes) {
    void* p = ws + ob;
    ob = (ob + bytes + 255) & ~(size_t)255;
    return p;
  };
  float* ya = (float*)alloc((size_t)N * DH * 4);
  float* yb = (float*)alloc((size_t)N * DH * 4);
  int* cnt = (int*)alloc((size_t)N * R_ET * 4);
  int* offs = (int*)alloc((size_t)(N + 1) * 4);
  int* cursor = (int*)alloc((size_t)N * 4);
  int* sorted = (int*)alloc((size_t)E * 4);
  float* scale = (float*)alloc((size_t)E * 4);
  float* u = (float*)alloc(1024);
  ushort* Abf = (ushort*)alloc((size_t)Npad * DH * 2);
  ushort* Wt = (ushort*)alloc((size_t)3 * 9 * DH * DH * 2);
  ushort* tbuf = (ushort*)alloc((size_t)R_ET * N * DH * 2);
  (void)ws_size;

  hipMemsetAsync(u, 0, 2 * DH * sizeof(float), stream);
  for (int l = 0; l < 3; l++)
    wconv_kernel<<<9, 256, 0, stream>>>(rootp[l], Wp[l], Wt + (size_t)l * 9 * DH * DH);

  dim3 ggrid(Npad / 128, R_ET + 1);
  dim3 egrid((E + 255) / 256);
  dim3 ngrid((N + 3) / 4);
  const int total = N * DH, padtotal = Npad * DH;
  dim3 agrid((padtotal / 4 + 255) / 256);

  for (int g = 0; g < 2; g++) {
    hipMemsetAsync(cnt, 0, (size_t)N * R_ET * sizeof(int), stream);
    count_kernel<<<egrid, 256, 0, stream>>>(ei[g], et[g], cnt, E);
    scan_kernel<<<1, 1024, 0, stream>>>(cnt, offs, cursor, N);
    place_kernel<<<egrid, 256, 0, stream>>>(ei[g], et[g], cnt, cursor, sorted, scale, E);
    for (int l = 0; l < 3; l++) {
      const float* Ai = (l == 0) ? x[g] : ((l == 1) ? ya : yb);
      float* yo = (l == 1) ? yb : ya;
      aconv_kernel<<<agrid, 256, 0, stream>>>(Ai, Abf, l > 0, total, padtotal);
      gemm_mfma<<<ggrid, 256, 0, stream>>>(Abf, Wt + (size_t)l * 9 * DH * DH,
                                           biasp[l], yo, tbuf, N);
      gather_kernel<<<ngrid, 256, 0, stream>>>(offs, sorted, scale, tbuf, yo, N);
    }
    pool_kernel<<<(N + 99) / 100, 256, 0, stream>>>(ya, u + g * DH, N);
  }
  mlp_kernel<<<1, 256, 0, stream>>>(u, fc1w, fc1b, fc2w, fc2b, (float*)d_out, N);
}

// Round 5
// 1051.923 us; speedup vs baseline: 4.9241x; 1.2757x over previous
//
#include <hip/hip_runtime.h>

#define R_ET 8
#define DH 128

typedef __bf16 bf16x8 __attribute__((ext_vector_type(8)));
typedef float f32x4 __attribute__((ext_vector_type(4)));

__device__ __forceinline__ ushort f2bf(float f) {
  unsigned u = __float_as_uint(f);
  u += 0x7fff + ((u >> 16) & 1);  // round-to-nearest-even
  return (ushort)(u >> 16);
}

// ---------------- degree count per (dst, etype) ----------------
__global__ void count_kernel(const int* __restrict__ ei, const int* __restrict__ et,
                             int* __restrict__ cnt, int E) {
  int e = blockIdx.x * blockDim.x + threadIdx.x;
  if (e < E) atomicAdd(&cnt[ei[E + e] * R_ET + et[e]], 1);
}

// ---------------- 3-phase device-wide exclusive scan of per-node degree ----------------
// Phase 1: per-block (1024 nodes) local exclusive scan + block total.
__global__ __launch_bounds__(1024) void scan1_kernel(const int* __restrict__ cnt,
                                                     int* __restrict__ off,
                                                     int* __restrict__ bsum, int N) {
  __shared__ int s[1024];
  int tid = threadIdx.x;
  int node = blockIdx.x * 1024 + tid;
  int d = 0;
  if (node < N) {
    const int4* c = (const int4*)&cnt[node * R_ET];
    int4 a = c[0], b = c[1];
    d = a.x + a.y + a.z + a.w + b.x + b.y + b.z + b.w;
  }
  s[tid] = d;
  __syncthreads();
  for (int step = 1; step < 1024; step <<= 1) {
    int v = (tid >= step) ? s[tid - step] : 0;
    __syncthreads();
    s[tid] += v;
    __syncthreads();
  }
  if (node < N) off[node] = s[tid] - d;  // exclusive within block
  if (tid == 1023) bsum[blockIdx.x] = s[1023];
}

// Phase 2: single-block exclusive scan of block sums (nb <= 1024).
__global__ __launch_bounds__(1024) void scan2_kernel(int* __restrict__ bsum, int nb) {
  __shared__ int s[1024];
  int tid = threadIdx.x;
  int v = (tid < nb) ? bsum[tid] : 0;
  s[tid] = v;
  __syncthreads();
  for (int step = 1; step < 1024; step <<= 1) {
    int x = (tid >= step) ? s[tid - step] : 0;
    __syncthreads();
    s[tid] += x;
    __syncthreads();
  }
  if (tid < nb) bsum[tid] = s[tid] - v;  // exclusive
}

// Phase 3: add block base, init cursor, off[N]=E.
__global__ __launch_bounds__(1024) void scan3_kernel(int* __restrict__ off,
                                                     int* __restrict__ cursor,
                                                     const int* __restrict__ bsum,
                                                     int N, int E) {
  int node = blockIdx.x * 1024 + threadIdx.x;
  if (node < N) {
    int o = off[node] + bsum[blockIdx.x];
    off[node] = o;
    cursor[node] = o;
  }
  if (node == 0) off[N] = E;  // total degree == E
}

// ---------------- place edges into dst-sorted slots ----------------
__global__ void place_kernel(const int* __restrict__ ei, const int* __restrict__ et,
                             const int* __restrict__ cnt, int* __restrict__ cursor,
                             int* __restrict__ sorted, float* __restrict__ scale, int E) {
  int e = blockIdx.x * blockDim.x + threadIdx.x;
  if (e >= E) return;
  int src = ei[e], dst = ei[E + e], r = et[e];
  int slot = atomicAdd(&cursor[dst], 1);
  sorted[slot] = src | (r << 28);  // src < 2^28, r < 8
  scale[slot] = 1.f / (float)cnt[dst * R_ET + r];
}

// ---------------- weight convert+transpose: Wt[mat][n][k] bf16 ----------------
__global__ __launch_bounds__(256) void wconv_kernel(const float* __restrict__ root,
                                                    const float* __restrict__ W,
                                                    ushort* __restrict__ Wt) {
  int mat = blockIdx.x;  // 0 = root, 1..8 = W[r]
  const float* src = (mat == 0) ? root : (W + (size_t)(mat - 1) * DH * DH);
  ushort* dst = Wt + (size_t)mat * DH * DH;
  for (int idx = threadIdx.x; idx < DH * DH; idx += 256) {
    int n = idx >> 7, k = idx & 127;
    dst[idx] = f2bf(src[k * DH + n]);
  }
}

// ---------------- activation convert (layer 0 only), zero-pads rows ----------------
__global__ __launch_bounds__(256) void aconv_kernel(const float* __restrict__ src,
                                                    ushort* __restrict__ dst,
                                                    int total, int padtotal) {
  int i4 = (blockIdx.x * 256 + threadIdx.x) * 4;
  if (i4 >= padtotal) return;
  ushort4 o = make_ushort4(0, 0, 0, 0);
  if (i4 < total) {
    float4 v = *(const float4*)&src[i4];
    o = make_ushort4(f2bf(v.x), f2bf(v.y), f2bf(v.z), f2bf(v.w));
  }
  *(ushort4*)&dst[i4] = o;
}

// ---------------- bf16 MFMA GEMM: y = A@root + bias ; t[r] = A@W[r] (bf16 out) ----------
// blockIdx.y = cb: 0 -> y (fp32), 1..8 -> t slab cb-1 (bf16). 128x128 tile, BK=32.
__global__ __launch_bounds__(256) void gemm_mfma(
    const ushort* __restrict__ Abf, const ushort* __restrict__ Wt,
    const float* __restrict__ bias, float* __restrict__ y,
    ushort* __restrict__ t, int N) {
  __shared__ ushort As[128 * 32];  // [row][kk] contiguous (global_load_lds order)
  __shared__ ushort Bs[128 * 32];  // [n][kk]
  const int tid = threadIdx.x;
  const int wave = tid >> 6, lane = tid & 63;
  const int quad = lane >> 4, l15 = lane & 15;
  const int cb = blockIdx.y;
  const int rbase = blockIdx.x * 128;
  const ushort* gB = Wt + (size_t)cb * (DH * DH);
  const int wr = (wave >> 1) * 64, wc = (wave & 1) * 64;

  f32x4 acc[4][4];
#pragma unroll
  for (int i = 0; i < 4; i++)
#pragma unroll
    for (int j = 0; j < 4; j++) acc[i][j] = (f32x4){0.f, 0.f, 0.f, 0.f};

  for (int kc = 0; kc < 4; kc++) {
    if (kc) __syncthreads();
#pragma unroll
    for (int it = 0; it < 2; it++) {
      int piece = it * 256 + tid;              // 512 x 16B pieces = 8 KB tile
      int row = piece >> 2, sub = piece & 3;
      const ushort* ga = Abf + ((size_t)(rbase + row) * DH + kc * 32 + sub * 8);
      const ushort* gb = gB + ((size_t)row * DH + kc * 32 + sub * 8);
      ushort* la = As + (size_t)(it * 256 + wave * 64) * 8;
      ushort* lb = Bs + (size_t)(it * 256 + wave * 64) * 8;
      __builtin_amdgcn_global_load_lds((const __attribute__((address_space(1))) void*)ga,
                                       (__attribute__((address_space(3))) void*)la, 16, 0, 0);
      __builtin_amdgcn_global_load_lds((const __attribute__((address_space(1))) void*)gb,
                                       (__attribute__((address_space(3))) void*)lb, 16, 0, 0);
    }
    __syncthreads();
    bf16x8 af[4], bfr[4];
#pragma unroll
    for (int i = 0; i < 4; i++) {
      af[i] = *(const bf16x8*)&As[(wr + i * 16 + l15) * 32 + quad * 8];
      bfr[i] = *(const bf16x8*)&Bs[(wc + i * 16 + l15) * 32 + quad * 8];
    }
#pragma unroll
    for (int i = 0; i < 4; i++)
#pragma unroll
      for (int j = 0; j < 4; j++)
        acc[i][j] = __builtin_amdgcn_mfma_f32_16x16x32_bf16(af[i], bfr[j], acc[i][j], 0, 0, 0);
  }

  if (cb == 0) {
#pragma unroll
    for (int j = 0; j < 4; j++) {
      int col = wc + j * 16 + l15;
      float bv = bias[col];
#pragma unroll
      for (int i = 0; i < 4; i++)
#pragma unroll
        for (int r = 0; r < 4; r++) {
          int row = rbase + wr + i * 16 + quad * 4 + r;
          if (row < N) y[(size_t)row * DH + col] = acc[i][j][r] + bv;
        }
    }
  } else {
    ushort* tp = t + (size_t)(cb - 1) * N * DH;
#pragma unroll
    for (int j = 0; j < 4; j++) {
      int col = wc + j * 16 + l15;
#pragma unroll
      for (int i = 0; i < 4; i++)
#pragma unroll
        for (int r = 0; r < 4; r++) {
          int row = rbase + wr + i * 16 + quad * 4 + r;
          if (row < N) tp[(size_t)row * DH + col] = f2bf(acc[i][j][r]);
        }
    }
  }
}

// ---------------- CSR gather (layers 0,1): Abf = bf16(relu(y + msgs)) ----------------
__global__ __launch_bounds__(256) void gather_mid(
    const int* __restrict__ off, const int* __restrict__ sorted,
    const float* __restrict__ scale, const ushort* __restrict__ t,
    const float* __restrict__ y, ushort* __restrict__ Abf, int N) {
  int dst = blockIdx.x * 4 + (threadIdx.x >> 6);
  if (dst >= N) return;
  int lane = threadIdx.x & 63;
  int start = off[dst], end = off[dst + 1];
  float ax = 0.f, ay = 0.f;
  for (int base = start; base < end; base += 64) {
    int m = min(64, end - base);
    int p = 0;
    float s = 0.f;
    if (lane < m) { p = sorted[base + lane]; s = scale[base + lane]; }
    for (int j = 0; j < m; j++) {
      int pj = __shfl(p, j);
      float sj = __shfl(s, j);
      int src = pj & 0x0fffffff, r = pj >> 28;
      unsigned u = *(const unsigned*)&t[((size_t)r * N + src) * DH + lane * 2];
      ax = fmaf(__uint_as_float(u << 16), sj, ax);
      ay = fmaf(__uint_as_float(u & 0xffff0000u), sj, ay);
    }
  }
  float2 yv = *(const float2*)&y[(size_t)dst * DH + lane * 2];
  float rx = fmaxf(yv.x + ax, 0.f);
  float ry = fmaxf(yv.y + ay, 0.f);
  unsigned o = (unsigned)f2bf(rx) | ((unsigned)f2bf(ry) << 16);
  *(unsigned*)&Abf[(size_t)dst * DH + lane * 2] = o;
}

// ---------------- CSR gather (layer 2): y += msgs (fp32, no relu) ----------------
__global__ __launch_bounds__(256) void gather_last(
    const int* __restrict__ off, const int* __restrict__ sorted,
    const float* __restrict__ scale, const ushort* __restrict__ t,
    float* __restrict__ y, int N) {
  int dst = blockIdx.x * 4 + (threadIdx.x >> 6);
  if (dst >= N) return;
  int lane = threadIdx.x & 63;
  int start = off[dst], end = off[dst + 1];
  float ax = 0.f, ay = 0.f;
  for (int base = start; base < end; base += 64) {
    int m = min(64, end - base);
    int p = 0;
    float s = 0.f;
    if (lane < m) { p = sorted[base + lane]; s = scale[base + lane]; }
    for (int j = 0; j < m; j++) {
      int pj = __shfl(p, j);
      float sj = __shfl(s, j);
      int src = pj & 0x0fffffff, r = pj >> 28;
      unsigned u = *(const unsigned*)&t[((size_t)r * N + src) * DH + lane * 2];
      ax = fmaf(__uint_as_float(u << 16), sj, ax);
      ay = fmaf(__uint_as_float(u & 0xffff0000u), sj, ay);
    }
  }
  float2* yp = (float2*)&y[(size_t)dst * DH + lane * 2];
  float2 yv = *yp;
  yv.x += ax;
  yv.y += ay;
  *yp = yv;
}

// ---------------- column sums for mean pool ----------------
__global__ __launch_bounds__(256) void pool_kernel(const float* __restrict__ y,
                                                   float* __restrict__ u, int N) {
  __shared__ float s[256];
  int tid = threadIdx.x;
  int c = tid & 127, rr = tid >> 7;
  int n0 = blockIdx.x * 100;
  int nend = min(n0 + 100, N);
  float sum = 0.f;
  for (int n = n0 + rr; n < nend; n += 2) sum += y[(size_t)n * DH + c];
  s[tid] = sum;
  __syncthreads();
  if (tid < 128) atomicAdd(&u[c], s[tid] + s[tid + 128]);
}

// ---------------- final MLP on concat(u1,u2)/N ----------------
__global__ __launch_bounds__(256) void mlp_kernel(
    const float* __restrict__ u, const float* __restrict__ fc1w,
    const float* __restrict__ fc1b, const float* __restrict__ fc2w,
    const float* __restrict__ fc2b, float* __restrict__ out, int N) {
  __shared__ float uin[256];
  __shared__ float hred[128];
  int tid = threadIdx.x;
  uin[tid] = u[tid] * (1.f / (float)N);
  __syncthreads();
  if (tid < 128) {
    float s = fc1b[tid];
    for (int i = 0; i < 256; i++) s = fmaf(uin[i], fc1w[i * 128 + tid], s);
    s = fmaxf(s, 0.f);
    hred[tid] = s * fc2w[tid];
  }
  __syncthreads();
  if (tid == 0) {
    float s = fc2b[0];
    for (int i = 0; i < 128; i++) s += hred[i];
    out[0] = s;
  }
}

extern "C" void kernel_launch(void* const* d_in, const int* in_sizes, int n_in,
                              void* d_out, int out_size, void* d_ws, size_t ws_size,
                              hipStream_t stream) {
  const float* x[2] = {(const float*)d_in[0], (const float*)d_in[3]};
  const int* ei[2] = {(const int*)d_in[1], (const int*)d_in[4]};
  const int* et[2] = {(const int*)d_in[2], (const int*)d_in[5]};
  const float* Wp[3] = {(const float*)d_in[6], (const float*)d_in[9], (const float*)d_in[12]};
  const float* rootp[3] = {(const float*)d_in[7], (const float*)d_in[10], (const float*)d_in[13]};
  const float* biasp[3] = {(const float*)d_in[8], (const float*)d_in[11], (const float*)d_in[14]};
  const float* fc1w = (const float*)d_in[15];
  const float* fc1b = (const float*)d_in[16];
  const float* fc2w = (const float*)d_in[17];
  const float* fc2b = (const float*)d_in[18];

  const int N = in_sizes[0] / DH;
  const int E = in_sizes[2];
  const int Npad = (N + 127) & ~127;
  const int NB = (N + 1023) / 1024;  // scan blocks (<=1024)

  char* ws = (char*)d_ws;
  size_t ob = 0;
  auto alloc = [&](size_t bytes) {
    void* p = ws + ob;
    ob = (ob + bytes + 255) & ~(size_t)255;
    return p;
  };
  float* y = (float*)alloc((size_t)N * DH * 4);
  int* cnt = (int*)alloc((size_t)N * R_ET * 4);
  int* offs = (int*)alloc((size_t)(N + 1) * 4);
  int* cursor = (int*)alloc((size_t)N * 4);
  int* bsum = (int*)alloc(1024 * 4);
  int* sorted = (int*)alloc((size_t)E * 4);
  float* scale = (float*)alloc((size_t)E * 4);
  float* u = (float*)alloc(1024);
  ushort* Abf = (ushort*)alloc((size_t)Npad * DH * 2);
  ushort* Wt = (ushort*)alloc((size_t)3 * 9 * DH * DH * 2);
  ushort* tbuf = (ushort*)alloc((size_t)R_ET * N * DH * 2);
  (void)ws_size;

  hipMemsetAsync(u, 0, 2 * DH * sizeof(float), stream);
  for (int l = 0; l < 3; l++)
    wconv_kernel<<<9, 256, 0, stream>>>(rootp[l], Wp[l], Wt + (size_t)l * 9 * DH * DH);

  dim3 ggrid(Npad / 128, R_ET + 1);
  dim3 egrid((E + 255) / 256);
  dim3 ngrid((N + 3) / 4);
  const int total = N * DH, padtotal = Npad * DH;
  dim3 agrid((padtotal / 4 + 255) / 256);

  for (int g = 0; g < 2; g++) {
    hipMemsetAsync(cnt, 0, (size_t)N * R_ET * sizeof(int), stream);
    count_kernel<<<egrid, 256, 0, stream>>>(ei[g], et[g], cnt, E);
    scan1_kernel<<<NB, 1024, 0, stream>>>(cnt, offs, bsum, N);
    scan2_kernel<<<1, 1024, 0, stream>>>(bsum, NB);
    scan3_kernel<<<NB, 1024, 0, stream>>>(offs, cursor, bsum, N, E);
    place_kernel<<<egrid, 256, 0, stream>>>(ei[g], et[g], cnt, cursor, sorted, scale, E);
    aconv_kernel<<<agrid, 256, 0, stream>>>(x[g], Abf, total, padtotal);
    for (int l = 0; l < 3; l++) {
      gemm_mfma<<<ggrid, 256, 0, stream>>>(Abf, Wt + (size_t)l * 9 * DH * DH,
                                           biasp[l], y, tbuf, N);
      if (l < 2) {
        gather_mid<<<ngrid, 256, 0, stream>>>(offs, sorted, scale, tbuf, y, Abf, N);
      } else {
        gather_last<<<ngrid, 256, 0, stream>>>(offs, sorted, scale, tbuf, y, N);
      }
    }
    pool_kernel<<<(N + 99) / 100, 256, 0, stream>>>(y, u + g * DH, N);
  }
  mlp_kernel<<<1, 256, 0, stream>>>(u, fc1w, fc1b, fc2w, fc2b, (float*)d_out, N);
}

// Round 6
// 887.623 us; speedup vs baseline: 5.8356x; 1.1851x over previous
//
#include <hip/hip_runtime.h>

#define R_ET 8
#define DH 128

typedef __bf16 bf16x8 __attribute__((ext_vector_type(8)));
typedef float f32x4 __attribute__((ext_vector_type(4)));

__device__ __forceinline__ ushort f2bf(float f) {
  unsigned u = __float_as_uint(f);
  u += 0x7fff + ((u >> 16) & 1);  // round-to-nearest-even
  return (ushort)(u >> 16);
}

// Swizzled activation/weight layout: element (row, k) lives at
//   row*128 + ((k>>3) ^ (row&7))*8 + (k&7)
// so the flat global_load_lds image gives conflict-free (2-way) b128 fragment reads.

// ---------------- degree count per (dst, etype) ----------------
__global__ void count_kernel(const int* __restrict__ ei, const int* __restrict__ et,
                             int* __restrict__ cnt, int E) {
  int e = blockIdx.x * blockDim.x + threadIdx.x;
  if (e < E) atomicAdd(&cnt[ei[E + e] * R_ET + et[e]], 1);
}

// ---------------- 3-phase device-wide exclusive scan of per-node degree ----------------
__global__ __launch_bounds__(1024) void scan1_kernel(const int* __restrict__ cnt,
                                                     int* __restrict__ off,
                                                     int* __restrict__ bsum, int N) {
  __shared__ int s[1024];
  int tid = threadIdx.x;
  int node = blockIdx.x * 1024 + tid;
  int d = 0;
  if (node < N) {
    const int4* c = (const int4*)&cnt[node * R_ET];
    int4 a = c[0], b = c[1];
    d = a.x + a.y + a.z + a.w + b.x + b.y + b.z + b.w;
  }
  s[tid] = d;
  __syncthreads();
  for (int step = 1; step < 1024; step <<= 1) {
    int v = (tid >= step) ? s[tid - step] : 0;
    __syncthreads();
    s[tid] += v;
    __syncthreads();
  }
  if (node < N) off[node] = s[tid] - d;
  if (tid == 1023) bsum[blockIdx.x] = s[1023];
}

__global__ __launch_bounds__(1024) void scan2_kernel(int* __restrict__ bsum, int nb) {
  __shared__ int s[1024];
  int tid = threadIdx.x;
  int v = (tid < nb) ? bsum[tid] : 0;
  s[tid] = v;
  __syncthreads();
  for (int step = 1; step < 1024; step <<= 1) {
    int x = (tid >= step) ? s[tid - step] : 0;
    __syncthreads();
    s[tid] += x;
    __syncthreads();
  }
  if (tid < nb) bsum[tid] = s[tid] - v;
}

__global__ __launch_bounds__(1024) void scan3_kernel(int* __restrict__ off,
                                                     int* __restrict__ cursor,
                                                     const int* __restrict__ bsum,
                                                     int N, int E) {
  int node = blockIdx.x * 1024 + threadIdx.x;
  if (node < N) {
    int o = off[node] + bsum[blockIdx.x];
    off[node] = o;
    cursor[node] = o;
  }
  if (node == 0) off[N] = E;
}

// ---------------- place edges into dst-sorted slots (packed metadata) ----------------
__global__ void place_kernel(const int* __restrict__ ei, const int* __restrict__ et,
                             const int* __restrict__ cnt, int* __restrict__ cursor,
                             int2* __restrict__ meta, int E) {
  int e = blockIdx.x * blockDim.x + threadIdx.x;
  if (e >= E) return;
  int src = ei[e], dst = ei[E + e], r = et[e];
  int slot = atomicAdd(&cursor[dst], 1);
  meta[slot] = make_int2(src | (r << 28),
                         __float_as_int(1.f / (float)cnt[dst * R_ET + r]));
}

// ---------------- weight convert+transpose: Wt[mat][n][k] bf16, swizzled ----------------
__global__ __launch_bounds__(256) void wconv_kernel(const float* __restrict__ root,
                                                    const float* __restrict__ W,
                                                    ushort* __restrict__ Wt) {
  int mat = blockIdx.x;  // 0 = root, 1..8 = W[r]
  const float* src = (mat == 0) ? root : (W + (size_t)(mat - 1) * DH * DH);
  ushort* dst = Wt + (size_t)mat * DH * DH;
  for (int idx = threadIdx.x; idx < DH * DH; idx += 256) {
    int n = idx >> 7, k = idx & 127;
    dst[n * DH + (((k >> 3) ^ (n & 7)) << 3) + (k & 7)] = f2bf(src[k * DH + n]);
  }
}

// ---------------- activation convert (layer 0), zero-pads rows, swizzled ----------------
__global__ __launch_bounds__(256) void aconv_kernel(const float* __restrict__ src,
                                                    ushort* __restrict__ dst,
                                                    int total, int padtotal) {
  int i4 = (blockIdx.x * 256 + threadIdx.x) * 4;
  if (i4 >= padtotal) return;
  int row = i4 >> 7, k = i4 & 127;
  ushort4 o = make_ushort4(0, 0, 0, 0);
  if (i4 < total) {
    float4 v = *(const float4*)&src[i4];
    o = make_ushort4(f2bf(v.x), f2bf(v.y), f2bf(v.z), f2bf(v.w));
  }
  *(ushort4*)&dst[(size_t)row * DH + (((k >> 3) ^ (row & 7)) << 3) + (k & 7)] = o;
}

// ---------------- bf16 MFMA GEMM, 3 matrices per block ----------------
// grid (Npad/128, 3); block y handles mats {3y, 3y+1, 3y+2}; mat 0 -> y (fp32+bias),
// mats 1..8 -> t slab mat-1 (bf16, plain row-major). A tile staged once, reused 3x.
__global__ __launch_bounds__(256) void gemm_mfma(
    const ushort* __restrict__ Abf, const ushort* __restrict__ Wt,
    const float* __restrict__ bias, float* __restrict__ y,
    ushort* __restrict__ t, int N) {
  __shared__ ushort As[128 * DH];  // 32 KB, swizzled image (flat copy of Abf tile)
  __shared__ ushort Bs[128 * DH];  // 32 KB, swizzled image of Wt[mat]
  const int tid = threadIdx.x;
  const int wave = tid >> 6, lane = tid & 63;
  const int quad = lane >> 4, l15 = lane & 15;
  const int rbase = blockIdx.x * 128;
  const int wr = (wave >> 1) * 64, wc = (wave & 1) * 64;

  const ushort* gA = Abf + (size_t)rbase * DH;
#pragma unroll
  for (int it = 0; it < 8; it++) {
    __builtin_amdgcn_global_load_lds(
        (const __attribute__((address_space(1))) void*)(gA + (it * 256 + tid) * 8),
        (__attribute__((address_space(3))) void*)(As + (it * 256 + wave * 64) * 8), 16, 0, 0);
  }

  for (int m = 0; m < 3; m++) {
    const int mat = blockIdx.y * 3 + m;
    const ushort* gB = Wt + (size_t)mat * DH * DH;
    if (m) __syncthreads();  // prior readers of Bs done
#pragma unroll
    for (int it = 0; it < 8; it++) {
      __builtin_amdgcn_global_load_lds(
          (const __attribute__((address_space(1))) void*)(gB + (it * 256 + tid) * 8),
          (__attribute__((address_space(3))) void*)(Bs + (it * 256 + wave * 64) * 8), 16, 0, 0);
    }
    __syncthreads();  // A (first iter) + B staged

    f32x4 acc[4][4];
#pragma unroll
    for (int i = 0; i < 4; i++)
#pragma unroll
      for (int j = 0; j < 4; j++) acc[i][j] = (f32x4){0.f, 0.f, 0.f, 0.f};

#pragma unroll
    for (int kc = 0; kc < 4; kc++) {
      bf16x8 af[4], bfr[4];
#pragma unroll
      for (int i = 0; i < 4; i++) {
        int ra = wr + i * 16 + l15;
        int rb = wc + i * 16 + l15;
        af[i] = *(const bf16x8*)&As[ra * DH + (((kc * 4 + quad) ^ (ra & 7)) << 3)];
        bfr[i] = *(const bf16x8*)&Bs[rb * DH + (((kc * 4 + quad) ^ (rb & 7)) << 3)];
      }
#pragma unroll
      for (int i = 0; i < 4; i++)
#pragma unroll
        for (int j = 0; j < 4; j++)
          acc[i][j] = __builtin_amdgcn_mfma_f32_16x16x32_bf16(af[i], bfr[j], acc[i][j], 0, 0, 0);
    }

    if (mat == 0) {
#pragma unroll
      for (int j = 0; j < 4; j++) {
        int col = wc + j * 16 + l15;
        float bv = bias[col];
#pragma unroll
        for (int i = 0; i < 4; i++)
#pragma unroll
          for (int r = 0; r < 4; r++) {
            int row = rbase + wr + i * 16 + quad * 4 + r;
            if (row < N) y[(size_t)row * DH + col] = acc[i][j][r] + bv;
          }
      }
    } else {
      ushort* tp = t + (size_t)(mat - 1) * N * DH;
#pragma unroll
      for (int j = 0; j < 4; j++) {
        int col = wc + j * 16 + l15;
#pragma unroll
        for (int i = 0; i < 4; i++)
#pragma unroll
          for (int r = 0; r < 4; r++) {
            int row = rbase + wr + i * 16 + quad * 4 + r;
            if (row < N) tp[(size_t)row * DH + col] = f2bf(acc[i][j][r]);
          }
      }
    }
  }
}

// ---------------- gather core: accumulate messages for one dst (wave-wide) ----------
__device__ __forceinline__ void gather_accum(const int2* __restrict__ meta,
                                             const ushort* __restrict__ t,
                                             int start, int end, int lane, int N,
                                             float& ax, float& ay) {
  const int colb = lane * 2;
  for (int base = start; base < end; base += 64) {
    int m = min(64, end - base);
    int2 md = make_int2(0, 0);
    if (lane < m) md = meta[base + lane];
    int j = 0;
    for (; j + 4 <= m; j += 4) {
      int p0 = __shfl(md.x, j),     q0 = __shfl(md.y, j);
      int p1 = __shfl(md.x, j + 1), q1 = __shfl(md.y, j + 1);
      int p2 = __shfl(md.x, j + 2), q2 = __shfl(md.y, j + 2);
      int p3 = __shfl(md.x, j + 3), q3 = __shfl(md.y, j + 3);
      unsigned u0 = *(const unsigned*)&t[(((size_t)((unsigned)p0 >> 28) * N + (p0 & 0x0fffffff)) << 7) + colb];
      unsigned u1 = *(const unsigned*)&t[(((size_t)((unsigned)p1 >> 28) * N + (p1 & 0x0fffffff)) << 7) + colb];
      unsigned u2 = *(const unsigned*)&t[(((size_t)((unsigned)p2 >> 28) * N + (p2 & 0x0fffffff)) << 7) + colb];
      unsigned u3 = *(const unsigned*)&t[(((size_t)((unsigned)p3 >> 28) * N + (p3 & 0x0fffffff)) << 7) + colb];
      float s0 = __int_as_float(q0), s1 = __int_as_float(q1);
      float s2 = __int_as_float(q2), s3 = __int_as_float(q3);
      ax = fmaf(__uint_as_float(u0 << 16), s0, ax);
      ay = fmaf(__uint_as_float(u0 & 0xffff0000u), s0, ay);
      ax = fmaf(__uint_as_float(u1 << 16), s1, ax);
      ay = fmaf(__uint_as_float(u1 & 0xffff0000u), s1, ay);
      ax = fmaf(__uint_as_float(u2 << 16), s2, ax);
      ay = fmaf(__uint_as_float(u2 & 0xffff0000u), s2, ay);
      ax = fmaf(__uint_as_float(u3 << 16), s3, ax);
      ay = fmaf(__uint_as_float(u3 & 0xffff0000u), s3, ay);
    }
    for (; j < m; j++) {
      int pj = __shfl(md.x, j);
      float sj = __int_as_float(__shfl(md.y, j));
      unsigned u = *(const unsigned*)&t[(((size_t)((unsigned)pj >> 28) * N + (pj & 0x0fffffff)) << 7) + colb];
      ax = fmaf(__uint_as_float(u << 16), sj, ax);
      ay = fmaf(__uint_as_float(u & 0xffff0000u), sj, ay);
    }
  }
}

// ---------------- CSR gather (layers 0,1): Abf = bf16(relu(y + msgs)), swizzled ------
__global__ __launch_bounds__(256) void gather_mid(
    const int* __restrict__ off, const int2* __restrict__ meta,
    const ushort* __restrict__ t, const float* __restrict__ y,
    ushort* __restrict__ Abf, int N) {
  int dst = blockIdx.x * 4 + (threadIdx.x >> 6);
  if (dst >= N) return;
  int lane = threadIdx.x & 63;
  float ax = 0.f, ay = 0.f;
  gather_accum(meta, t, off[dst], off[dst + 1], lane, N, ax, ay);
  float2 yv = *(const float2*)&y[(size_t)dst * DH + lane * 2];
  float rx = fmaxf(yv.x + ax, 0.f);
  float ry = fmaxf(yv.y + ay, 0.f);
  unsigned o = (unsigned)f2bf(rx) | ((unsigned)f2bf(ry) << 16);
  int k = lane * 2;
  *(unsigned*)&Abf[(size_t)dst * DH + (((k >> 3) ^ (dst & 7)) << 3) + (k & 7)] = o;
}

// ---------------- CSR gather (layer 2): y += msgs (fp32, no relu) ----------------
__global__ __launch_bounds__(256) void gather_last(
    const int* __restrict__ off, const int2* __restrict__ meta,
    const ushort* __restrict__ t, float* __restrict__ y, int N) {
  int dst = blockIdx.x * 4 + (threadIdx.x >> 6);
  if (dst >= N) return;
  int lane = threadIdx.x & 63;
  float ax = 0.f, ay = 0.f;
  gather_accum(meta, t, off[dst], off[dst + 1], lane, N, ax, ay);
  float2* yp = (float2*)&y[(size_t)dst * DH + lane * 2];
  float2 yv = *yp;
  yv.x += ax;
  yv.y += ay;
  *yp = yv;
}

// ---------------- column sums for mean pool ----------------
__global__ __launch_bounds__(256) void pool_kernel(const float* __restrict__ y,
                                                   float* __restrict__ u, int N) {
  __shared__ float s[256];
  int tid = threadIdx.x;
  int c = tid & 127, rr = tid >> 7;
  int n0 = blockIdx.x * 100;
  int nend = min(n0 + 100, N);
  float sum = 0.f;
  for (int n = n0 + rr; n < nend; n += 2) sum += y[(size_t)n * DH + c];
  s[tid] = sum;
  __syncthreads();
  if (tid < 128) atomicAdd(&u[c], s[tid] + s[tid + 128]);
}

// ---------------- final MLP on concat(u1,u2)/N ----------------
__global__ __launch_bounds__(256) void mlp_kernel(
    const float* __restrict__ u, const float* __restrict__ fc1w,
    const float* __restrict__ fc1b, const float* __restrict__ fc2w,
    const float* __restrict__ fc2b, float* __restrict__ out, int N) {
  __shared__ float uin[256];
  __shared__ float hred[128];
  int tid = threadIdx.x;
  uin[tid] = u[tid] * (1.f / (float)N);
  __syncthreads();
  if (tid < 128) {
    float s = fc1b[tid];
    for (int i = 0; i < 256; i++) s = fmaf(uin[i], fc1w[i * 128 + tid], s);
    s = fmaxf(s, 0.f);
    hred[tid] = s * fc2w[tid];
  }
  __syncthreads();
  if (tid == 0) {
    float s = fc2b[0];
    for (int i = 0; i < 128; i++) s += hred[i];
    out[0] = s;
  }
}

extern "C" void kernel_launch(void* const* d_in, const int* in_sizes, int n_in,
                              void* d_out, int out_size, void* d_ws, size_t ws_size,
                              hipStream_t stream) {
  const float* x[2] = {(const float*)d_in[0], (const float*)d_in[3]};
  const int* ei[2] = {(const int*)d_in[1], (const int*)d_in[4]};
  const int* et[2] = {(const int*)d_in[2], (const int*)d_in[5]};
  const float* Wp[3] = {(const float*)d_in[6], (const float*)d_in[9], (const float*)d_in[12]};
  const float* rootp[3] = {(const float*)d_in[7], (const float*)d_in[10], (const float*)d_in[13]};
  const float* biasp[3] = {(const float*)d_in[8], (const float*)d_in[11], (const float*)d_in[14]};
  const float* fc1w = (const float*)d_in[15];
  const float* fc1b = (const float*)d_in[16];
  const float* fc2w = (const float*)d_in[17];
  const float* fc2b = (const float*)d_in[18];

  const int N = in_sizes[0] / DH;
  const int E = in_sizes[2];
  const int Npad = (N + 127) & ~127;
  const int NB = (N + 1023) / 1024;

  char* ws = (char*)d_ws;
  size_t ob = 0;
  auto alloc = [&](size_t bytes) {
    void* p = ws + ob;
    ob = (ob + bytes + 255) & ~(size_t)255;
    return p;
  };
  float* y = (float*)alloc((size_t)N * DH * 4);
  int* cnt = (int*)alloc((size_t)N * R_ET * 4);
  int* offs = (int*)alloc((size_t)(N + 1) * 4);
  int* cursor = (int*)alloc((size_t)N * 4);
  int* bsum = (int*)alloc(1024 * 4);
  int2* meta = (int2*)alloc((size_t)E * 8);
  float* u = (float*)alloc(1024);
  ushort* Abf = (ushort*)alloc((size_t)Npad * DH * 2);
  ushort* Wt = (ushort*)alloc((size_t)3 * 9 * DH * DH * 2);
  ushort* tbuf = (ushort*)alloc((size_t)R_ET * N * DH * 2);
  (void)ws_size;

  hipMemsetAsync(u, 0, 2 * DH * sizeof(float), stream);
  for (int l = 0; l < 3; l++)
    wconv_kernel<<<9, 256, 0, stream>>>(rootp[l], Wp[l], Wt + (size_t)l * 9 * DH * DH);

  dim3 ggrid(Npad / 128, 3);
  dim3 egrid((E + 255) / 256);
  dim3 ngrid((N + 3) / 4);
  const int total = N * DH, padtotal = Npad * DH;
  dim3 agrid((padtotal / 4 + 255) / 256);

  for (int g = 0; g < 2; g++) {
    hipMemsetAsync(cnt, 0, (size_t)N * R_ET * sizeof(int), stream);
    count_kernel<<<egrid, 256, 0, stream>>>(ei[g], et[g], cnt, E);
    scan1_kernel<<<NB, 1024, 0, stream>>>(cnt, offs, bsum, N);
    scan2_kernel<<<1, 1024, 0, stream>>>(bsum, NB);
    scan3_kernel<<<NB, 1024, 0, stream>>>(offs, cursor, bsum, N, E);
    place_kernel<<<egrid, 256, 0, stream>>>(ei[g], et[g], cnt, cursor, meta, E);
    aconv_kernel<<<agrid, 256, 0, stream>>>(x[g], Abf, total, padtotal);
    for (int l = 0; l < 3; l++) {
      gemm_mfma<<<ggrid, 256, 0, stream>>>(Abf, Wt + (size_t)l * 9 * DH * DH,
                                           biasp[l], y, tbuf, N);
      if (l < 2) {
        gather_mid<<<ngrid, 256, 0, stream>>>(offs, meta, tbuf, y, Abf, N);
      } else {
        gather_last<<<ngrid, 256, 0, stream>>>(offs, meta, tbuf, y, N);
      }
    }
    pool_kernel<<<(N + 99) / 100, 256, 0, stream>>>(y, u + g * DH, N);
  }
  mlp_kernel<<<1, 256, 0, stream>>>(u, fc1w, fc1b, fc2w, fc2b, (float*)d_out, N);
}